// Round 6
// baseline (7437.492 us; speedup 1.0000x reference)
//
#include <hip/hip_runtime.h>
#include <hip/hip_cooperative_groups.h>

namespace cg = cooperative_groups;

// LowRankAttention: B=2,H=12 (BH=24), S=8192, D=64, RANK=16, 10 steps, fp32.
#define S_ 8192
#define D_ 64
#define BH_ 24
#define NBLK (BH_ * 32)   // 768 blocks x 256 threads = one thread per (row,col) per bh

static constexpr float INV_S2 = 1.0f / (8192.0f * 8192.0f);
static constexpr float STEPSZ = 1000.0f;
static constexpr float CC = 2.0f * INV_S2;

#define LP_N (BH_ * S_ * 16)
#define PART_STRIDE 2576   // LQ[a*16+l] 0..1023, LL[l*16+c] 1024..1279; R-side +1280; N 2560
#define PART_N (NBLK * PART_STRIDE)
#define ACCF_STRIDE 2624   // MLL 0, MLQ 256, RRS 1280, KRT 1536, C1 2560, C2 2576, SRN 2592
#define ACCF_N (BH_ * ACCF_STRIDE)
#define PART2_STRIDE 1040  // RV[d*16+l] 0..1023, N 1024
#define PART2_N (NBLK * PART2_STRIDE)

// ---------------------------------------------------------------------------
// Low-VGPR block reduction. KIND 0: LQ+LL from (L,q); 1: KR+RR+N from (rp2,key);
// 2: RV+N from (rp2,v).  Lane owns column pair a = 2*(t&31),+1; each wave covers
// 64 rows (half-wave row split), shfl_xor(32) completes the wave partial.
// B must be >= 5440 floats; stage [256][16] overlays the red area.
// ---------------------------------------------------------------------------
template <int KIND>
__device__ __forceinline__ void reduceSideW(const float* __restrict__ sb, int j0, int t,
                                            const float* vals, float* B,
                                            float* __restrict__ pbase) {
  const int tc2 = t & 31, tcx = t & 15, trw = t >> 5, w = t >> 6, lane = t & 63;
  {
    float4* st = (float4*)(B + t * 16);
    st[0] = make_float4(vals[0], vals[1], vals[2], vals[3]);
    st[1] = make_float4(vals[4], vals[5], vals[6], vals[7]);
    st[2] = make_float4(vals[8], vals[9], vals[10], vals[11]);
    st[3] = make_float4(vals[12], vals[13], vals[14], vals[15]);
  }
  __syncthreads();
  float aQ0[16], aQ1[16], aX[16], aN[16];
#pragma unroll
  for (int l = 0; l < 16; ++l) { aQ0[l] = 0.f; aQ1[l] = 0.f; aX[l] = 0.f; aN[l] = 0.f; }
  for (int it = 0; it < 32; ++it) {
    int jl = trw + (it << 3);
    const float4* Vw = (const float4*)(B + jl * 16);
    float4 b0 = Vw[0], b1 = Vw[1], b2 = Vw[2], b3 = Vw[3];
    float Vv[16] = {b0.x,b0.y,b0.z,b0.w, b1.x,b1.y,b1.z,b1.w,
                    b2.x,b2.y,b2.z,b2.w, b3.x,b3.y,b3.z,b3.w};
    float xc = (KIND < 2) ? B[jl * 16 + tcx] : 0.f;
    float2 qv = *(const float2*)(sb + (size_t)(j0 + jl) * D_ + (tc2 << 1));
#pragma unroll
    for (int l = 0; l < 16; ++l) {
      aQ0[l] += Vv[l] * qv.x;
      aQ1[l] += Vv[l] * qv.y;
      if (KIND < 2) aX[l] += Vv[l] * xc;
      if (KIND >= 1) aN[l] += Vv[l];
    }
  }
#pragma unroll
  for (int l = 0; l < 16; ++l) {
    aQ0[l] += __shfl_xor(aQ0[l], 32);
    aQ1[l] += __shfl_xor(aQ1[l], 32);
    if (KIND < 2) aX[l] += __shfl_xor(aX[l], 32);
    if (KIND >= 1) aN[l] += __shfl_xor(aN[l], 32);
  }
  __syncthreads();   // stage consumed; overlay red
  float* rg = B + w * 1360;
  if (lane < 32) {
    float* p = rg + lane * 33;
#pragma unroll
    for (int l = 0; l < 16; ++l) { p[l] = aQ0[l]; p[16 + l] = aQ1[l]; }
  }
  if (KIND < 2 && lane < 16) {
    float* p = rg + 1056 + lane * 17;
#pragma unroll
    for (int l = 0; l < 16; ++l) p[l] = aX[l];
  }
  if (KIND >= 1 && lane == 0) {
#pragma unroll
    for (int l = 0; l < 16; ++l) rg[1328 + l] = aN[l];
  }
  __syncthreads();
#pragma unroll
  for (int r = 0; r < 4; ++r) {
    int o = t + r * 256;
    int tcg = o >> 5, e = o & 31, c = e >> 4, l = e & 15;
    int idx = tcg * 33 + c * 16 + l;
    float s = B[idx] + B[1360 + idx] + B[2720 + idx] + B[4080 + idx];
    pbase[((tcg << 1) + c) * 16 + l] = s;   // [a*16+l]
  }
  if (KIND < 2) {
    int cx = t >> 4, l = t & 15;
    int idx = 1056 + cx * 17 + l;
    pbase[1024 + l * 16 + cx] = B[idx] + B[1360 + idx] + B[2720 + idx] + B[4080 + idx];
  }
  if (KIND >= 1 && t < 16) {
    int idx = 1328 + t;
    pbase[(KIND == 1 ? 1280 : 1024) + t] =
        B[idx] + B[1360 + idx] + B[2720 + idx] + B[4080 + idx];
  }
  __syncthreads();
}

// M: RRS[k][l] (256) + KRT[a][l] (1024)
__device__ __forceinline__ void rowUpdate(const float* M, const float4* q4, float lv[16]) {
  const float4* RR4 = (const float4*)M;
  const float4* KR4 = (const float4*)(M + 256);
  float n2 = 0.f;
#pragma unroll
  for (int l = 0; l < 16; ++l) n2 += lv[l] * lv[l];
  float ri = rsqrtf(n2);
  float ls[16], L[16];
#pragma unroll
  for (int l = 0; l < 16; ++l) { ls[l] = lv[l] * ri; L[l] = ls[l] * ls[l]; }
  float dl[16];
#pragma unroll
  for (int l = 0; l < 16; ++l) dl[l] = 0.f;
#pragma unroll
  for (int k = 0; k < 16; ++k) {
    float Lk = L[k];
#pragma unroll
    for (int g = 0; g < 4; ++g) {
      float4 rr = RR4[k * 4 + g];
      dl[4*g+0] += Lk * rr.x; dl[4*g+1] += Lk * rr.y;
      dl[4*g+2] += Lk * rr.z; dl[4*g+3] += Lk * rr.w;
    }
  }
#pragma unroll
  for (int a4 = 0; a4 < 16; ++a4) {
    float4 qq = q4[a4];
#pragma unroll
    for (int c = 0; c < 4; ++c) {
      float qa = (c == 0) ? qq.x : (c == 1) ? qq.y : (c == 2) ? qq.z : qq.w;
      int a = a4 * 4 + c;
#pragma unroll
      for (int g = 0; g < 4; ++g) {
        float4 kr = KR4[a * 4 + g];
        dl[4*g+0] -= qa * kr.x; dl[4*g+1] -= qa * kr.y;
        dl[4*g+2] -= qa * kr.z; dl[4*g+3] -= qa * kr.w;
      }
    }
  }
  float dot = 0.f;
#pragma unroll
  for (int l = 0; l < 16; ++l) { dl[l] *= ls[l]; dot += ls[l] * dl[l]; }
#pragma unroll
  for (int l = 0; l < 16; ++l) lv[l] -= STEPSZ * (dl[l] - ls[l] * dot) * ri;
}

// M: MLL (256) + MLQ (1024); C: C1(16), C2(16), SRN(16)
__device__ __forceinline__ void colUpdateB(const float* M, const float* C,
                                           const float4* k4, float nv[16]) {
  const float4* MLL4 = (const float4*)M;
  const float4* MLQ4 = (const float4*)(M + 256);
  const float* C1 = C;
  const float* C2 = C + 16;
  const float* SRN = C + 32;
  float rp2[16];
#pragma unroll
  for (int l = 0; l < 16; ++l) rp2[l] = nv[l] * nv[l];
  float s[16];
#pragma unroll
  for (int k = 0; k < 16; ++k) {
    float a0 = 0.f;
#pragma unroll
    for (int g = 0; g < 4; ++g) {
      float4 m = MLL4[k * 4 + g];
      a0 += m.x * rp2[4*g+0] + m.y * rp2[4*g+1] + m.z * rp2[4*g+2] + m.w * rp2[4*g+3];
    }
    s[k] = a0;
  }
#pragma unroll
  for (int a4 = 0; a4 < 16; ++a4) {
    float4 kk = k4[a4];
#pragma unroll
    for (int k = 0; k < 16; ++k) {
      float4 m = MLQ4[k * 16 + a4];
      s[k] -= m.x * kk.x + m.y * kk.y + m.z * kk.z + m.w * kk.w;
    }
  }
#pragma unroll
  for (int k = 0; k < 16; ++k) {
    float rs = nv[k] * SRN[k];
    float d2 = rs * s[k];
    nv[k] = C1[k] * nv[k] - C2[k] * d2;
  }
}

// sh >= 2608 floats: raw 0..2575, inn 2576.., srn 2592..
__device__ __forceinline__ void kB_body(const float* __restrict__ part,
                                        float* __restrict__ accF, int bb, int t, float* sh) {
  float* raw = sh;
  float* inn = sh + 2576;
  float* srn = sh + 2592;
  const float* p0 = part + (size_t)bb * 32 * PART_STRIDE;
  for (int vI = t; vI < PART_STRIDE; vI += 256) {
    float s = 0.f;
    const float* p = p0 + vI;
#pragma unroll 8
    for (int b2 = 0; b2 < 32; ++b2) s += p[(size_t)b2 * PART_STRIDE];
    raw[vI] = s;
  }
  __syncthreads();
  if (t < 16) {
    float N = raw[2560 + t];
    inn[t] = 1.0f / N;
    srn[t] = rsqrtf(N);
  }
  __syncthreads();
  float* o = accF + (size_t)bb * ACCF_STRIDE;
  o[t] = raw[1024 + t] * CC * inn[t & 15];                        // MLL
  o[1280 + t] = raw[2304 + t] * CC * inn[t >> 4] * inn[t & 15];   // RRS
#pragma unroll
  for (int r = 0; r < 4; ++r) {
    int e = t + r * 256;
    o[256 + e] = raw[((e & 63) << 4) + (e >> 6)] * CC;            // MLQ[k*64+a]
  }
#pragma unroll
  for (int r = 0; r < 4; ++r) {
    int e = t + r * 256;
    o[1536 + e] = raw[1280 + e] * CC * inn[e & 15];               // KRT[a*16+l]
  }
  if (t < 16) {
    int k = t;
    float s = 0.f;
#pragma unroll
    for (int l = 0; l < 16; ++l)
      s += raw[1024 + k * 16 + l] * CC * inn[l] * raw[2304 + k * 16 + l];
#pragma unroll
    for (int a = 0; a < 64; ++a)
      s -= raw[a * 16 + k] * CC * raw[1280 + a * 16 + k];
    float PJ = inn[k] * s;
    o[2560 + t] = 1.0f + STEPSZ * PJ * inn[t];
    o[2576 + t] = STEPSZ * srn[t];
    o[2592 + t] = srn[t];
  }
}

__device__ __forceinline__ void kBF_body(const float* __restrict__ part2,
                                         float* __restrict__ RVs, int bb, int t, float* sh) {
  float* raw = sh;
  float* inn = sh + 1040;
  const float* p0 = part2 + (size_t)bb * 32 * PART2_STRIDE;
  for (int vI = t; vI < PART2_STRIDE; vI += 256) {
    float s = 0.f;
    const float* p = p0 + vI;
#pragma unroll 8
    for (int b2 = 0; b2 < 32; ++b2) s += p[(size_t)b2 * PART2_STRIDE];
    raw[vI] = s;
  }
  __syncthreads();
  if (t < 16) inn[t] = 1.0f / raw[1024 + t];
  __syncthreads();
#pragma unroll
  for (int r = 0; r < 4; ++r) {
    int e = t + r * 256;  // e = k*64+d ; RV raw at [d*16+k]
    RVs[(size_t)bb * 1024 + e] = raw[((e & 63) << 4) + (e >> 6)] * inn[e >> 6];
  }
}

// ---------------------------------------------------------------------------
// Cooperative persistent kernel (primary path)
// ---------------------------------------------------------------------------
__global__ void __launch_bounds__(256, 4)
kFused(const float* __restrict__ q, const float* __restrict__ key,
       const float* __restrict__ vv, const float* __restrict__ lp0,
       const float* __restrict__ rp0, float* __restrict__ out,
       float* __restrict__ part, float* __restrict__ accF,
       float* __restrict__ part2, float* __restrict__ RVs) {
  cg::grid_group grid = cg::this_grid();
  const int b = blockIdx.x, t = threadIdx.x;
  const int bh = b >> 5, bx = b & 31;
  const int j0 = bx * 256, j = j0 + t;
  __shared__ float B[6400];

  const float* qb = q + (size_t)bh * S_ * D_;
  const float* kb = key + (size_t)bh * S_ * D_;
  const float* vb = vv + (size_t)bh * S_ * D_;
  const float* A = accF + (size_t)bh * ACCF_STRIDE;
  const float4* q4 = (const float4*)(qb + (size_t)j * D_);
  const float4* k4 = (const float4*)(kb + (size_t)j * D_);

  float lv[16], nv[16];
  {
    const float4* s4 = (const float4*)(lp0 + ((size_t)bh * S_ + j) * 16);
    float4 a0 = s4[0], a1 = s4[1], a2 = s4[2], a3 = s4[3];
    lv[0]=a0.x; lv[1]=a0.y; lv[2]=a0.z; lv[3]=a0.w;
    lv[4]=a1.x; lv[5]=a1.y; lv[6]=a1.z; lv[7]=a1.w;
    lv[8]=a2.x; lv[9]=a2.y; lv[10]=a2.z; lv[11]=a2.w;
    lv[12]=a3.x; lv[13]=a3.y; lv[14]=a3.z; lv[15]=a3.w;
    const float* rsrc = rp0 + (size_t)bh * 16 * S_ + j;
#pragma unroll
    for (int k = 0; k < 16; ++k) nv[k] = rsrc[(size_t)k * S_];
  }

  for (int s = 0; s <= 10; ++s) {
    if (s > 0) {
      for (int e = t; e < 2608; e += 256) B[e] = A[e];
      __syncthreads();
      rowUpdate(B + 1280, q4, lv);
      colUpdateB(B, B + 2560, k4, nv);
      __syncthreads();
    }
    if (s < 10) {
      float L[16];
      {
        float m2 = 0.f;
#pragma unroll
        for (int l = 0; l < 16; ++l) m2 += lv[l] * lv[l];
        float r2 = 1.0f / m2;
#pragma unroll
        for (int l = 0; l < 16; ++l) L[l] = lv[l] * lv[l] * r2;
      }
      reduceSideW<0>(qb, j0, t, L, B, part + (size_t)b * PART_STRIDE);
      float rp2[16];
#pragma unroll
      for (int l = 0; l < 16; ++l) rp2[l] = nv[l] * nv[l];
      reduceSideW<1>(kb, j0, t, rp2, B, part + (size_t)b * PART_STRIDE + 1280);
    } else {
      float rp2[16];
#pragma unroll
      for (int l = 0; l < 16; ++l) rp2[l] = nv[l] * nv[l];
      reduceSideW<2>(vb, j0, t, rp2, B, part2 + (size_t)b * PART2_STRIDE);
    }
    __threadfence();
    grid.sync();
    if (b < BH_) {
      if (s < 10) kB_body(part, accF, b, t, B);
      else        kBF_body(part2, RVs, b, t, B);
    }
    __threadfence();
    grid.sync();
  }

  // epilogue: out[j][d] = sum_k unit(lv)^2[k] * RVs[bh][k][d]
#pragma unroll
  for (int r = 0; r < 4; ++r) B[t + r * 256] = RVs[(size_t)bh * 1024 + t + r * 256];
  __syncthreads();
  float n2 = 0.f;
#pragma unroll
  for (int l = 0; l < 16; ++l) n2 += lv[l] * lv[l];
  float r2 = 1.0f / n2;
  float L[16];
#pragma unroll
  for (int l = 0; l < 16; ++l) L[l] = lv[l] * lv[l] * r2;
  float o[64];
#pragma unroll
  for (int d = 0; d < 64; ++d) o[d] = 0.f;
  const float4* rv4 = (const float4*)B;
#pragma unroll
  for (int k = 0; k < 16; ++k) {
    float Lk = L[k];
#pragma unroll
    for (int d4 = 0; d4 < 16; ++d4) {
      float4 r = rv4[k * 16 + d4];
      o[4*d4+0] += Lk * r.x; o[4*d4+1] += Lk * r.y;
      o[4*d4+2] += Lk * r.z; o[4*d4+3] += Lk * r.w;
    }
  }
  float4* o4 = (float4*)(out + ((size_t)bh * S_ + j) * D_);
#pragma unroll
  for (int d4 = 0; d4 < 16; ++d4)
    o4[d4] = make_float4(o[4*d4+0], o[4*d4+1], o[4*d4+2], o[4*d4+3]);
}

// ---------------------------------------------------------------------------
// Fallback multi-kernel path (proven R4 structure, shared device bodies)
// ---------------------------------------------------------------------------
template <int MODE>  // 0 init, 1 mid, 2 last
__global__ void __launch_bounds__(256) kStepF(const float* __restrict__ accF,
                                              const float* __restrict__ q,
                                              const float* __restrict__ key,
                                              const float* __restrict__ vv,
                                              const float* __restrict__ lp_src,
                                              const float* __restrict__ rp_src,
                                              float* __restrict__ lp_dst,
                                              float* __restrict__ rp_dst,
                                              float* __restrict__ part,
                                              float* __restrict__ part2) {
  const int bh = blockIdx.y, bx = blockIdx.x, t = threadIdx.x;
  const int j0 = bx * 256, j = j0 + t;
  const int bb = bh * 32 + bx;
  __shared__ float B[6400];
  const float* A = accF + (size_t)bh * ACCF_STRIDE;
  const float* qb = q + (size_t)bh * S_ * D_;
  const float* kb = key + (size_t)bh * S_ * D_;

  if (blockIdx.z == 0) {
    const size_t base = ((size_t)bh * S_ + j) * 16;
    float lv[16];
    if (MODE >= 1) {
      for (int e = t; e < 1280; e += 256) B[e] = A[1280 + e];  // RRS + KRT
      __syncthreads();
      const float4* s4 = (const float4*)(lp_src + base);
      float4 a0 = s4[0], a1 = s4[1], a2 = s4[2], a3 = s4[3];
      lv[0]=a0.x; lv[1]=a0.y; lv[2]=a0.z; lv[3]=a0.w;
      lv[4]=a1.x; lv[5]=a1.y; lv[6]=a1.z; lv[7]=a1.w;
      lv[8]=a2.x; lv[9]=a2.y; lv[10]=a2.z; lv[11]=a2.w;
      lv[12]=a3.x; lv[13]=a3.y; lv[14]=a3.z; lv[15]=a3.w;
      rowUpdate(B, (const float4*)(qb + (size_t)j * D_), lv);
      float4* d4 = (float4*)(lp_dst + base);
      d4[0] = make_float4(lv[0], lv[1], lv[2], lv[3]);
      d4[1] = make_float4(lv[4], lv[5], lv[6], lv[7]);
      d4[2] = make_float4(lv[8], lv[9], lv[10], lv[11]);
      d4[3] = make_float4(lv[12], lv[13], lv[14], lv[15]);
      if (MODE == 2) return;
      __syncthreads();
    } else {
      const float4* s4 = (const float4*)(lp_src + base);
      float4 a0 = s4[0], a1 = s4[1], a2 = s4[2], a3 = s4[3];
      lv[0]=a0.x; lv[1]=a0.y; lv[2]=a0.z; lv[3]=a0.w;
      lv[4]=a1.x; lv[5]=a1.y; lv[6]=a1.z; lv[7]=a1.w;
      lv[8]=a2.x; lv[9]=a2.y; lv[10]=a2.z; lv[11]=a2.w;
      lv[12]=a3.x; lv[13]=a3.y; lv[14]=a3.z; lv[15]=a3.w;
      float4* d4 = (float4*)(lp_dst + base);
      d4[0] = make_float4(lv[0], lv[1], lv[2], lv[3]);
      d4[1] = make_float4(lv[4], lv[5], lv[6], lv[7]);
      d4[2] = make_float4(lv[8], lv[9], lv[10], lv[11]);
      d4[3] = make_float4(lv[12], lv[13], lv[14], lv[15]);
    }
    float L[16];
    {
      float m2 = 0.f;
#pragma unroll
      for (int l = 0; l < 16; ++l) m2 += lv[l] * lv[l];
      float r2 = 1.0f / m2;
#pragma unroll
      for (int l = 0; l < 16; ++l) L[l] = lv[l] * lv[l] * r2;
    }
    reduceSideW<0>(qb, j0, t, L, B, part + (size_t)bb * PART_STRIDE);
  } else {
    const size_t cb = ((size_t)bh * S_ + j) * 16;  // transposed rp [i][16]
    float nv[16];
    if (MODE >= 1) {
      for (int e = t; e < 1328; e += 256) B[e] = (e < 1280) ? A[e] : A[1280 + e];
      __syncthreads();
      const float4* r4 = (const float4*)(rp_src + cb);
      float4 a0 = r4[0], a1 = r4[1], a2 = r4[2], a3 = r4[3];
      nv[0]=a0.x; nv[1]=a0.y; nv[2]=a0.z; nv[3]=a0.w;
      nv[4]=a1.x; nv[5]=a1.y; nv[6]=a1.z; nv[7]=a1.w;
      nv[8]=a2.x; nv[9]=a2.y; nv[10]=a2.z; nv[11]=a2.w;
      nv[12]=a3.x; nv[13]=a3.y; nv[14]=a3.z; nv[15]=a3.w;
      colUpdateB(B, B + 1280, (const float4*)(kb + (size_t)j * D_), nv);
      float4* d4 = (float4*)(rp_dst + cb);
      d4[0] = make_float4(nv[0], nv[1], nv[2], nv[3]);
      d4[1] = make_float4(nv[4], nv[5], nv[6], nv[7]);
      d4[2] = make_float4(nv[8], nv[9], nv[10], nv[11]);
      d4[3] = make_float4(nv[12], nv[13], nv[14], nv[15]);
      __syncthreads();
    } else {
      const float* rsrc = rp_src + (size_t)bh * 16 * S_ + j;  // original [r][S]
#pragma unroll
      for (int k = 0; k < 16; ++k) nv[k] = rsrc[(size_t)k * S_];
      float4* d4 = (float4*)(rp_dst + cb);
      d4[0] = make_float4(nv[0], nv[1], nv[2], nv[3]);
      d4[1] = make_float4(nv[4], nv[5], nv[6], nv[7]);
      d4[2] = make_float4(nv[8], nv[9], nv[10], nv[11]);
      d4[3] = make_float4(nv[12], nv[13], nv[14], nv[15]);
    }
    float rp2[16];
#pragma unroll
    for (int l = 0; l < 16; ++l) rp2[l] = nv[l] * nv[l];
    if (MODE < 2)
      reduceSideW<1>(kb, j0, t, rp2, B, part + (size_t)bb * PART_STRIDE + 1280);
    else
      reduceSideW<2>(vv + (size_t)bh * S_ * D_, j0, t, rp2, B,
                     part2 + (size_t)bb * PART2_STRIDE);
  }
}

__global__ void __launch_bounds__(256) kBk(const float* __restrict__ part,
                                           float* __restrict__ accF) {
  __shared__ float sh[2608];
  kB_body(part, accF, blockIdx.x, threadIdx.x, sh);
}

__global__ void __launch_bounds__(256) kBFk(const float* __restrict__ part2,
                                            float* __restrict__ RVs) {
  __shared__ float sh[1056];
  kBF_body(part2, RVs, blockIdx.x, threadIdx.x, sh);
}

__global__ void __launch_bounds__(256) kOutF(const float* __restrict__ lp,
                                             const float* __restrict__ RVs,
                                             float* __restrict__ out) {
  const int bh = blockIdx.y, t = threadIdx.x;
  __shared__ float rvs[1024];
#pragma unroll
  for (int r = 0; r < 4; ++r) rvs[t + r * 256] = RVs[(size_t)bh * 1024 + t + r * 256];
  __syncthreads();
  const int j = blockIdx.x * 256 + t;
  size_t base = ((size_t)bh * S_ + j) * 16;
  const float4* lp4 = (const float4*)(lp + base);
  float4 a0 = lp4[0], a1 = lp4[1], a2 = lp4[2], a3 = lp4[3];
  float lv[16] = {a0.x,a0.y,a0.z,a0.w, a1.x,a1.y,a1.z,a1.w,
                  a2.x,a2.y,a2.z,a2.w, a3.x,a3.y,a3.z,a3.w};
  float n2 = 0.f;
#pragma unroll
  for (int l = 0; l < 16; ++l) n2 += lv[l] * lv[l];
  float r2 = 1.0f / n2;
  float L[16];
#pragma unroll
  for (int l = 0; l < 16; ++l) L[l] = lv[l] * lv[l] * r2;
  float o[64];
#pragma unroll
  for (int d = 0; d < 64; ++d) o[d] = 0.f;
  const float4* rv4 = (const float4*)rvs;
#pragma unroll
  for (int k = 0; k < 16; ++k) {
    float Lk = L[k];
#pragma unroll
    for (int d4 = 0; d4 < 16; ++d4) {
      float4 r = rv4[k * 16 + d4];
      o[4*d4+0] += Lk * r.x; o[4*d4+1] += Lk * r.y;
      o[4*d4+2] += Lk * r.z; o[4*d4+3] += Lk * r.w;
    }
  }
  float4* o4 = (float4*)(out + ((size_t)bh * S_ + j) * D_);
#pragma unroll
  for (int d4 = 0; d4 < 16; ++d4)
    o4[d4] = make_float4(o[4*d4+0], o[4*d4+1], o[4*d4+2], o[4*d4+3]);
}

extern "C" void kernel_launch(void* const* d_in, const int* in_sizes, int n_in,
                              void* d_out, int out_size, void* d_ws, size_t ws_size,
                              hipStream_t stream) {
  (void)in_sizes; (void)n_in; (void)out_size; (void)ws_size;
  const float* q = (const float*)d_in[0];
  const float* key = (const float*)d_in[1];
  const float* v = (const float*)d_in[2];
  const float* lp0 = (const float*)d_in[3];
  const float* rp0 = (const float*)d_in[4];
  float* out = (float*)d_out;
  float* ws = (float*)d_ws;

  float* lp = ws;                  // fallback only
  float* rp = lp + LP_N;           // fallback only (transposed [i][16])
  float* part = rp + LP_N;
  float* accF = part + PART_N;
  float* part2 = accF + ACCF_N;
  float* RVs = part2 + PART2_N;
  // total 9,156,096 floats = 36.6 MB

  void* args[] = {(void*)&q, (void*)&key, (void*)&v, (void*)&lp0, (void*)&rp0,
                  (void*)&out, (void*)&part, (void*)&accF, (void*)&part2, (void*)&RVs};
  hipError_t err = hipLaunchCooperativeKernel((const void*)kFused, dim3(NBLK), dim3(256),
                                              args, 0, stream);
  if (err != hipSuccess) {
    (void)hipGetLastError();  // clear sticky error; use proven multi-kernel path
    dim3 blk(256);
    dim3 gS(32, BH_, 2);
    kStepF<0><<<gS, blk, 0, stream>>>(accF, q, key, v, lp0, rp0, lp, rp, part, part2);
    for (int s = 0; s < 10; ++s) {
      kBk<<<dim3(BH_), blk, 0, stream>>>(part, accF);
      if (s < 9)
        kStepF<1><<<gS, blk, 0, stream>>>(accF, q, key, v, lp, rp, lp, rp, part, part2);
      else
        kStepF<2><<<gS, blk, 0, stream>>>(accF, q, key, v, lp, rp, lp, rp, part, part2);
    }
    kBFk<<<dim3(BH_), blk, 0, stream>>>(part2, RVs);
    kOutF<<<dim3(32, BH_), blk, 0, stream>>>(lp, RVs, out);
  }
}

// Round 8
// 935.080 us; speedup vs baseline: 7.9539x; 7.9539x over previous
//
#include <hip/hip_runtime.h>

// LowRankAttention: B=2,H=12 (BH=24), S=8192, D=64, RANK=16, 10 steps, fp32.
// Multi-kernel pipeline; merged row+col blocks; one-column-per-lane reductions.
#define S_ 8192
#define D_ 64
#define BH_ 24

static constexpr float INV_S2 = 1.0f / (8192.0f * 8192.0f);
static constexpr float STEPSZ = 1000.0f;
static constexpr float CC = 2.0f * INV_S2;

#define LP_N (BH_ * S_ * 16)
#define PART_STRIDE 2576   // LQ[a*16+l] 0..1023, LL[l*16+c] 1024..1279; R-side +1280; N 2560
#define PART_N (BH_ * 32 * PART_STRIDE)
#define ACCF_STRIDE 2624   // MLL 0, MLQ 256, RRS 1280, KRT 1536, C1 2560, C2 2576, SRN 2592
#define ACCF_N (BH_ * ACCF_STRIDE)
#define PART2_STRIDE 1040  // RV[d*16+l] 0..1023, N 1024
#define PART2_N (BH_ * 32 * PART2_STRIDE)

#define STG 20             // stage stride (floats): 16B-aligned, 8 banks -> <=8-way on write
// LDS layout: MAT[0..2607] resident matrices; WK[0..5599] stage(5120)/red(5600) time-shared
#define WK_OFF 2608
#define LDS_FLOATS (WK_OFF + 5600)   // 8208 floats = 32.8 KB -> 4 blocks/CU

// ---------------------------------------------------------------------------
// Block reduction, one-column-per-lane (D=64 = wave width).
// KIND 0: LQ+LL from (L,q); 1: KR+RR+N from (rp2,key); 2: RV+N from (rp2,v).
// Lane owns stream column a = lane; wave w covers rows w*64..w*64+63.
// All LDS reads in the loop are wave-broadcast (conflict-free).
// ---------------------------------------------------------------------------
template <int KIND>
__device__ __forceinline__ void reduceSideW(const float* __restrict__ sb, int j0, int t,
                                            const float* vals, float* WK,
                                            float* __restrict__ pbase) {
  const int lane = t & 63, w = t >> 6, tcx = t & 15;
  {
    float4* st = (float4*)(WK + t * STG);
    st[0] = make_float4(vals[0], vals[1], vals[2], vals[3]);
    st[1] = make_float4(vals[4], vals[5], vals[6], vals[7]);
    st[2] = make_float4(vals[8], vals[9], vals[10], vals[11]);
    st[3] = make_float4(vals[12], vals[13], vals[14], vals[15]);
  }
  __syncthreads();
  float aQ[16], aX[16], aN[16];
#pragma unroll
  for (int l = 0; l < 16; ++l) { aQ[l] = 0.f; aX[l] = 0.f; aN[l] = 0.f; }
#pragma unroll 4
  for (int it = 0; it < 64; ++it) {
    const int jl = (w << 6) + it;
    const float4* Vw = (const float4*)(WK + jl * STG);
    float4 b0 = Vw[0], b1 = Vw[1], b2 = Vw[2], b3 = Vw[3];
    float Vv[16] = {b0.x,b0.y,b0.z,b0.w, b1.x,b1.y,b1.z,b1.w,
                    b2.x,b2.y,b2.z,b2.w, b3.x,b3.y,b3.z,b3.w};
    float xq = sb[(size_t)(j0 + jl) * D_ + lane];       // coalesced 256B/wave
    float xc = (KIND < 2) ? WK[jl * STG + tcx] : 0.f;   // broadcast per 16-lane group
#pragma unroll
    for (int l = 0; l < 16; ++l) {
      aQ[l] += Vv[l] * xq;
      if (KIND < 2) aX[l] += Vv[l] * xc;
      if (KIND >= 1) aN[l] += Vv[l];
    }
  }
  __syncthreads();   // stage consumed; overlay red
  float* rg = WK + w * 1400;
  {
    float* p = rg + lane * 17;
#pragma unroll
    for (int l = 0; l < 16; ++l) p[l] = aQ[l];
  }
  if (KIND < 2 && lane < 16) {
    float* p = rg + 1088 + lane * 17;
#pragma unroll
    for (int l = 0; l < 16; ++l) p[l] = aX[l];
  }
  if (KIND >= 1 && lane == 0) {
#pragma unroll
    for (int l = 0; l < 16; ++l) rg[1360 + l] = aN[l];
  }
  __syncthreads();
#pragma unroll
  for (int r = 0; r < 4; ++r) {
    int o = t + r * 256;
    int a = o >> 4, l = o & 15;
    int idx = a * 17 + l;
    pbase[a * 16 + l] = WK[idx] + WK[1400 + idx] + WK[2800 + idx] + WK[4200 + idx];
  }
  if (KIND < 2) {
    int c = t >> 4, l = t & 15;
    int idx = 1088 + c * 17 + l;
    pbase[1024 + l * 16 + c] = WK[idx] + WK[1400 + idx] + WK[2800 + idx] + WK[4200 + idx];
  }
  if (KIND >= 1 && t < 16) {
    int idx = 1360 + t;
    pbase[(KIND == 1 ? 1280 : 1024) + t] =
        WK[idx] + WK[1400 + idx] + WK[2800 + idx] + WK[4200 + idx];
  }
  __syncthreads();
}

// M: RRS[k][l] (256) + KRT[a][l] (1024)
__device__ __forceinline__ void rowUpdate(const float* M, const float4* q4, float lv[16]) {
  const float4* RR4 = (const float4*)M;
  const float4* KR4 = (const float4*)(M + 256);
  float n2 = 0.f;
#pragma unroll
  for (int l = 0; l < 16; ++l) n2 += lv[l] * lv[l];
  float ri = rsqrtf(n2);
  float ls[16], L[16];
#pragma unroll
  for (int l = 0; l < 16; ++l) { ls[l] = lv[l] * ri; L[l] = ls[l] * ls[l]; }
  float dl[16];
#pragma unroll
  for (int l = 0; l < 16; ++l) dl[l] = 0.f;
#pragma unroll
  for (int k = 0; k < 16; ++k) {
    float Lk = L[k];
#pragma unroll
    for (int g = 0; g < 4; ++g) {
      float4 rr = RR4[k * 4 + g];
      dl[4*g+0] += Lk * rr.x; dl[4*g+1] += Lk * rr.y;
      dl[4*g+2] += Lk * rr.z; dl[4*g+3] += Lk * rr.w;
    }
  }
#pragma unroll
  for (int a4 = 0; a4 < 16; ++a4) {
    float4 qq = q4[a4];
#pragma unroll
    for (int c = 0; c < 4; ++c) {
      float qa = (c == 0) ? qq.x : (c == 1) ? qq.y : (c == 2) ? qq.z : qq.w;
      int a = a4 * 4 + c;
#pragma unroll
      for (int g = 0; g < 4; ++g) {
        float4 kr = KR4[a * 4 + g];
        dl[4*g+0] -= qa * kr.x; dl[4*g+1] -= qa * kr.y;
        dl[4*g+2] -= qa * kr.z; dl[4*g+3] -= qa * kr.w;
      }
    }
  }
  float dot = 0.f;
#pragma unroll
  for (int l = 0; l < 16; ++l) { dl[l] *= ls[l]; dot += ls[l] * dl[l]; }
#pragma unroll
  for (int l = 0; l < 16; ++l) lv[l] -= STEPSZ * (dl[l] - ls[l] * dot) * ri;
}

// M: MLL (256) + MLQ (1024); C: C1(16), C2(16), SRN(16)
__device__ __forceinline__ void colUpdateB(const float* M, const float* C,
                                           const float4* k4, float nv[16]) {
  const float4* MLL4 = (const float4*)M;
  const float4* MLQ4 = (const float4*)(M + 256);
  const float* C1 = C;
  const float* C2 = C + 16;
  const float* SRN = C + 32;
  float rp2[16];
#pragma unroll
  for (int l = 0; l < 16; ++l) rp2[l] = nv[l] * nv[l];
  float s[16];
#pragma unroll
  for (int k = 0; k < 16; ++k) {
    float a0 = 0.f;
#pragma unroll
    for (int g = 0; g < 4; ++g) {
      float4 m = MLL4[k * 4 + g];
      a0 += m.x * rp2[4*g+0] + m.y * rp2[4*g+1] + m.z * rp2[4*g+2] + m.w * rp2[4*g+3];
    }
    s[k] = a0;
  }
#pragma unroll
  for (int a4 = 0; a4 < 16; ++a4) {
    float4 kk = k4[a4];
#pragma unroll
    for (int k = 0; k < 16; ++k) {
      float4 m = MLQ4[k * 16 + a4];
      s[k] -= m.x * kk.x + m.y * kk.y + m.z * kk.z + m.w * kk.w;
    }
  }
#pragma unroll
  for (int k = 0; k < 16; ++k) {
    float rs = nv[k] * SRN[k];
    float d2 = rs * s[k];
    nv[k] = C1[k] * nv[k] - C2[k] * d2;
  }
}

// ---------------------------------------------------------------------------
// kStep<MODE>: merged row+col block. MODE 0 init (copy-in), 1 mid, 2 last.
// grid (32, BH_), block 256, all 768 blocks co-resident (4/CU capacity).
// ---------------------------------------------------------------------------
template <int MODE>
__global__ void __launch_bounds__(256) kStep(const float* __restrict__ accF,
                                             const float* __restrict__ q,
                                             const float* __restrict__ key,
                                             const float* __restrict__ vv,
                                             const float* __restrict__ lp0,
                                             const float* __restrict__ rp0,
                                             float* __restrict__ lp,
                                             float* __restrict__ rp,
                                             float* __restrict__ part,
                                             float* __restrict__ part2) {
  const int bh = blockIdx.y, bx = blockIdx.x, t = threadIdx.x;
  const int j0 = bx * 256, j = j0 + t;
  const int bb = bh * 32 + bx;
  __shared__ float B[LDS_FLOATS];
  float* MAT = B;
  float* WK = B + WK_OFF;
  const float* A = accF + (size_t)bh * ACCF_STRIDE;
  const float* qb = q + (size_t)bh * S_ * D_;
  const float* kb = key + (size_t)bh * S_ * D_;
  const size_t base = ((size_t)bh * S_ + j) * 16;

  if (MODE >= 1) {
    for (int e = t; e < 2608; e += 256) MAT[e] = A[e];
    __syncthreads();
  }

  // ================= row phase =================
  {
    float lv[16];
    const float4* s4 = (const float4*)((MODE == 0 ? lp0 : lp) + base);
    float4 a0 = s4[0], a1 = s4[1], a2 = s4[2], a3 = s4[3];
    lv[0]=a0.x; lv[1]=a0.y; lv[2]=a0.z; lv[3]=a0.w;
    lv[4]=a1.x; lv[5]=a1.y; lv[6]=a1.z; lv[7]=a1.w;
    lv[8]=a2.x; lv[9]=a2.y; lv[10]=a2.z; lv[11]=a2.w;
    lv[12]=a3.x; lv[13]=a3.y; lv[14]=a3.z; lv[15]=a3.w;
    if (MODE >= 1) {
      rowUpdate(MAT + 1280, (const float4*)(qb + (size_t)j * D_), lv);
    }
    float4* d4 = (float4*)(lp + base);
    d4[0] = make_float4(lv[0], lv[1], lv[2], lv[3]);
    d4[1] = make_float4(lv[4], lv[5], lv[6], lv[7]);
    d4[2] = make_float4(lv[8], lv[9], lv[10], lv[11]);
    d4[3] = make_float4(lv[12], lv[13], lv[14], lv[15]);
    if (MODE < 2) {
      float L[16];
      float m2 = 0.f;
#pragma unroll
      for (int l = 0; l < 16; ++l) m2 += lv[l] * lv[l];
      float r2 = 1.0f / m2;
#pragma unroll
      for (int l = 0; l < 16; ++l) L[l] = lv[l] * lv[l] * r2;
      reduceSideW<0>(qb, j0, t, L, WK, part + (size_t)bb * PART_STRIDE);
    }
  }

  // ================= col phase =================
  {
    float nv[16];
    if (MODE == 0) {
      const float* rsrc = rp0 + (size_t)bh * 16 * S_ + j;   // original [r][S]
#pragma unroll
      for (int k = 0; k < 16; ++k) nv[k] = rsrc[(size_t)k * S_];
    } else {
      const float4* r4 = (const float4*)(rp + base);        // transposed [i][16]
      float4 a0 = r4[0], a1 = r4[1], a2 = r4[2], a3 = r4[3];
      nv[0]=a0.x; nv[1]=a0.y; nv[2]=a0.z; nv[3]=a0.w;
      nv[4]=a1.x; nv[5]=a1.y; nv[6]=a1.z; nv[7]=a1.w;
      nv[8]=a2.x; nv[9]=a2.y; nv[10]=a2.z; nv[11]=a2.w;
      nv[12]=a3.x; nv[13]=a3.y; nv[14]=a3.z; nv[15]=a3.w;
      colUpdateB(MAT, MAT + 2560, (const float4*)(kb + (size_t)j * D_), nv);
    }
    float4* d4 = (float4*)(rp + base);
    d4[0] = make_float4(nv[0], nv[1], nv[2], nv[3]);
    d4[1] = make_float4(nv[4], nv[5], nv[6], nv[7]);
    d4[2] = make_float4(nv[8], nv[9], nv[10], nv[11]);
    d4[3] = make_float4(nv[12], nv[13], nv[14], nv[15]);
    float rp2[16];
#pragma unroll
    for (int l = 0; l < 16; ++l) rp2[l] = nv[l] * nv[l];
    if (MODE < 2)
      reduceSideW<1>(kb, j0, t, rp2, WK, part + (size_t)bb * PART_STRIDE + 1280);
    else
      reduceSideW<2>(vv + (size_t)bh * S_ * D_, j0, t, rp2, WK,
                     part2 + (size_t)bb * PART2_STRIDE);
  }
}

// ---------------------------------------------------------------------------
// kB: one block per bh. Sum 32 partials -> derived matrices + analytic PJ, c1/c2.
// ---------------------------------------------------------------------------
__global__ void __launch_bounds__(256) kB(const float* __restrict__ part,
                                          float* __restrict__ accF) {
  const int bh = blockIdx.x, t = threadIdx.x;
  __shared__ float raw[PART_STRIDE];
  __shared__ float inn[16], srn[16];
  const float* p0 = part + (size_t)bh * 32 * PART_STRIDE;
  for (int vI = t; vI < PART_STRIDE; vI += 256) {
    float s = 0.f;
    const float* p = p0 + vI;
#pragma unroll 8
    for (int b2 = 0; b2 < 32; ++b2) s += p[(size_t)b2 * PART_STRIDE];
    raw[vI] = s;
  }
  __syncthreads();
  if (t < 16) {
    float N = raw[2560 + t];
    inn[t] = 1.0f / N;
    srn[t] = rsqrtf(N);
  }
  __syncthreads();
  float* o = accF + (size_t)bh * ACCF_STRIDE;
  o[t] = raw[1024 + t] * CC * inn[t & 15];                        // MLL
  o[1280 + t] = raw[2304 + t] * CC * inn[t >> 4] * inn[t & 15];   // RRS
#pragma unroll
  for (int r = 0; r < 4; ++r) {
    int e = t + r * 256;
    o[256 + e] = raw[((e & 63) << 4) + (e >> 6)] * CC;            // MLQ[k*64+a]
  }
#pragma unroll
  for (int r = 0; r < 4; ++r) {
    int e = t + r * 256;
    o[1536 + e] = raw[1280 + e] * CC * inn[e & 15];               // KRT[a*16+l]
  }
  if (t < 16) {
    int k = t;
    float s = 0.f;
#pragma unroll
    for (int l = 0; l < 16; ++l)
      s += raw[1024 + k * 16 + l] * CC * inn[l] * raw[2304 + k * 16 + l];
#pragma unroll
    for (int a = 0; a < 64; ++a)
      s -= raw[a * 16 + k] * CC * raw[1280 + a * 16 + k];
    float PJ = inn[k] * s;
    o[2560 + t] = 1.0f + STEPSZ * PJ * inn[t];
    o[2576 + t] = STEPSZ * srn[t];
    o[2592 + t] = srn[t];
  }
}

// ---------------------------------------------------------------------------
// kBF: sum RV partials, scale by 1/N -> RVs[k*64+d]
// ---------------------------------------------------------------------------
__global__ void __launch_bounds__(256) kBF(const float* __restrict__ part2,
                                           float* __restrict__ RVs) {
  const int bh = blockIdx.x, t = threadIdx.x;
  __shared__ float raw[PART2_STRIDE];
  __shared__ float inn[16];
  const float* p0 = part2 + (size_t)bh * 32 * PART2_STRIDE;
  for (int vI = t; vI < PART2_STRIDE; vI += 256) {
    float s = 0.f;
    const float* p = p0 + vI;
#pragma unroll 8
    for (int b2 = 0; b2 < 32; ++b2) s += p[(size_t)b2 * PART2_STRIDE];
    raw[vI] = s;
  }
  __syncthreads();
  if (t < 16) inn[t] = 1.0f / raw[1024 + t];
  __syncthreads();
#pragma unroll
  for (int r = 0; r < 4; ++r) {
    int e = t + r * 256;  // e = k*64+d ; RV raw at [d*16+k]
    RVs[(size_t)bh * 1024 + e] = raw[((e & 63) << 4) + (e >> 6)] * inn[e >> 6];
  }
}

// out[j][d] = sum_k unit(lp_j)^2[k] * RVs[bh][k][d]
__global__ void __launch_bounds__(256) kOut(const float* __restrict__ lp,
                                            const float* __restrict__ RVs,
                                            float* __restrict__ out) {
  const int bh = blockIdx.y, t = threadIdx.x;
  __shared__ float rvs[1024];
#pragma unroll
  for (int r = 0; r < 4; ++r) rvs[t + r * 256] = RVs[(size_t)bh * 1024 + t + r * 256];
  __syncthreads();
  const int j = blockIdx.x * 256 + t;
  size_t base = ((size_t)bh * S_ + j) * 16;
  const float4* lp4 = (const float4*)(lp + base);
  float4 a0 = lp4[0], a1 = lp4[1], a2 = lp4[2], a3 = lp4[3];
  float lv[16] = {a0.x,a0.y,a0.z,a0.w, a1.x,a1.y,a1.z,a1.w,
                  a2.x,a2.y,a2.z,a2.w, a3.x,a3.y,a3.z,a3.w};
  float n2 = 0.f;
#pragma unroll
  for (int l = 0; l < 16; ++l) n2 += lv[l] * lv[l];
  float r2 = 1.0f / n2;
  float L[16];
#pragma unroll
  for (int l = 0; l < 16; ++l) L[l] = lv[l] * lv[l] * r2;
  float o[64];
#pragma unroll
  for (int d = 0; d < 64; ++d) o[d] = 0.f;
  const float4* rv4 = (const float4*)rvs;
#pragma unroll
  for (int k = 0; k < 16; ++k) {
    float Lk = L[k];
#pragma unroll
    for (int d4 = 0; d4 < 16; ++d4) {
      float4 r = rv4[k * 16 + d4];
      o[4*d4+0] += Lk * r.x; o[4*d4+1] += Lk * r.y;
      o[4*d4+2] += Lk * r.z; o[4*d4+3] += Lk * r.w;
    }
  }
  float4* o4 = (float4*)(out + ((size_t)bh * S_ + j) * D_);
#pragma unroll
  for (int d4 = 0; d4 < 16; ++d4)
    o4[d4] = make_float4(o[4*d4+0], o[4*d4+1], o[4*d4+2], o[4*d4+3]);
}

extern "C" void kernel_launch(void* const* d_in, const int* in_sizes, int n_in,
                              void* d_out, int out_size, void* d_ws, size_t ws_size,
                              hipStream_t stream) {
  (void)in_sizes; (void)n_in; (void)out_size; (void)ws_size;
  const float* q = (const float*)d_in[0];
  const float* key = (const float*)d_in[1];
  const float* v = (const float*)d_in[2];
  const float* lp0 = (const float*)d_in[3];
  const float* rp0 = (const float*)d_in[4];
  float* out = (float*)d_out;
  float* ws = (float*)d_ws;

  float* lp = ws;                  // 3,145,728 floats (internal [j][16])
  float* rp = lp + LP_N;           // 3,145,728 (transposed [i][16])
  float* part = rp + LP_N;         // 1,978,368
  float* accF = part + PART_N;     // 62,976
  float* part2 = accF + ACCF_N;    // 798,720
  float* RVs = part2 + PART2_N;    // 24,576
  // total 9,156,096 floats = 36.6 MB

  dim3 blk(256);
  dim3 gS(32, BH_);
  kStep<0><<<gS, blk, 0, stream>>>(accF, q, key, v, lp0, rp0, lp, rp, part, part2);
  for (int s = 0; s < 10; ++s) {
    kB<<<dim3(BH_), blk, 0, stream>>>(part, accF);
    if (s < 9)
      kStep<1><<<gS, blk, 0, stream>>>(accF, q, key, v, lp0, rp0, lp, rp, part, part2);
    else
      kStep<2><<<gS, blk, 0, stream>>>(accF, q, key, v, lp0, rp0, lp, rp, part, part2);
  }
  kBF<<<dim3(BH_), blk, 0, stream>>>(part2, RVs);
  kOut<<<gS, blk, 0, stream>>>(lp, RVs, out);
}